// Round 2
// baseline (399.570 us; speedup 1.0000x reference)
//
#include <hip/hip_runtime.h>
#include <hip/hip_bf16.h>

typedef __bf16 bf16x8 __attribute__((ext_vector_type(8)));
typedef __bf16 bf16x4 __attribute__((ext_vector_type(4)));
typedef float f32x4 __attribute__((ext_vector_type(4)));
typedef float f32x16 __attribute__((ext_vector_type(16)));

#define MFMA16(a,b,c) __builtin_amdgcn_mfma_f32_16x16x32_bf16((a),(b),(c),0,0,0)
#define MFMA32(a,b,c) __builtin_amdgcn_mfma_f32_32x32x16_bf16((a),(b),(c),0,0,0)

// async global->LDS, 16B per lane; lds dst = wave-uniform base + lane*16
__device__ __forceinline__ void gload_lds16(const void* g, void* l) {
    __builtin_amdgcn_global_load_lds((const __attribute__((address_space(1))) unsigned int*)g,
                                     (__attribute__((address_space(3))) unsigned int*)l, 16, 0, 0);
}

// ---------------- GroupNorm stats, stage 1 ----------------
__global__ __launch_bounds__(256) void gn_stats1(const float* __restrict__ x,
                                                 float* __restrict__ pstats) {
    int blk = blockIdx.x;            // 0..511
    int bg = blk >> 4, sl = blk & 15;
    int b = bg >> 3, g = bg & 7;
    const float* base = x + ((size_t)b * 4096 + sl * 256) * 256 + g * 32;
    float s = 0.f, s2 = 0.f;
    for (int i = threadIdx.x; i < 2048; i += 256) {
        int pos = i >> 3, f4 = i & 7;
        float4 v = *(const float4*)(base + (size_t)pos * 256 + f4 * 4);
        s  += v.x + v.y + v.z + v.w;
        s2 += v.x * v.x + v.y * v.y + v.z * v.z + v.w * v.w;
    }
    for (int off = 32; off; off >>= 1) {
        s  += __shfl_down(s, off);
        s2 += __shfl_down(s2, off);
    }
    __shared__ float red[8];
    int wave = threadIdx.x >> 6, lane = threadIdx.x & 63;
    if (lane == 0) { red[wave] = s; red[4 + wave] = s2; }
    __syncthreads();
    if (threadIdx.x == 0) {
        pstats[blk * 2]     = red[0] + red[1] + red[2] + red[3];
        pstats[blk * 2 + 1] = red[4] + red[5] + red[6] + red[7];
    }
}

// ---------------- GroupNorm stats, stage 2 ----------------
__global__ void gn_stats2(const float* __restrict__ pstats, float* __restrict__ stats) {
    int bg = threadIdx.x;
    if (bg < 32) {
        float S = 0.f, S2 = 0.f;
        for (int sl = 0; sl < 16; sl++) {
            S  += pstats[(bg * 16 + sl) * 2];
            S2 += pstats[(bg * 16 + sl) * 2 + 1];
        }
        const float invN = 1.f / 131072.f;
        float mean = S * invN;
        float var = S2 * invN - mean * mean;
        stats[bg * 2] = mean;
        stats[bg * 2 + 1] = rsqrtf(var + 1e-3f);
    }
}

// ---------------- GroupNorm normalize ----------------
__global__ __launch_bounds__(256) void gn_norm(const float* __restrict__ x,
                                               const float* __restrict__ gamma,
                                               const float* __restrict__ beta,
                                               const float* __restrict__ stats,
                                               float* __restrict__ xn_f32,
                                               __bf16* __restrict__ xn_bf) {
    size_t idx = (size_t)blockIdx.x * 256 + threadIdx.x;
    int c4 = (int)(idx & 63);
    int row = (int)(idx >> 6);
    int b = row >> 12;
    int g = c4 >> 3;
    float mean = stats[(b * 8 + g) * 2];
    float rstd = stats[(b * 8 + g) * 2 + 1];
    float4 xv = ((const float4*)x)[idx];
    float4 ga = ((const float4*)gamma)[c4];
    float4 be = ((const float4*)beta)[c4];
    float4 r;
    r.x = (xv.x - mean) * rstd * ga.x + be.x;
    r.y = (xv.y - mean) * rstd * ga.y + be.y;
    r.z = (xv.z - mean) * rstd * ga.z + be.z;
    r.w = (xv.w - mean) * rstd * ga.w + be.w;
    ((float4*)xn_f32)[idx] = r;
    bf16x4 o;
    o[0] = (__bf16)r.x; o[1] = (__bf16)r.y; o[2] = (__bf16)r.z; o[3] = (__bf16)r.w;
    *(bf16x4*)(xn_bf + idx * 4) = o;
}

// ---------------- Weight prep: fp32 [k][n] -> bf16 fragment-linear ----------------
__global__ __launch_bounds__(256) void prep_w(const float* __restrict__ Wq,
                                              const float* __restrict__ Wk,
                                              const float* __restrict__ Wv,
                                              const float* __restrict__ Wp,
                                              __bf16* __restrict__ wt) {
    int o = blockIdx.x * 256 + threadIdx.x;  // 0..262143
    int w = o >> 16;
    int rem = o & 65535;
    int nt   = rem >> 12;
    int kf   = (rem >> 9) & 7;
    int quad = (rem >> 7) & 3;
    int l16  = (rem >> 3) & 15;
    int j    = rem & 7;
    int n = nt * 16 + l16;
    int k = kf * 32 + quad * 8 + j;
    const float* W = (w == 0) ? Wq : (w == 1) ? Wk : (w == 2) ? Wv : Wp;
    wt[o] = (__bf16)W[k * 256 + n];
}

// ---------------- QKV GEMM: LDS A-tile; v stored transposed via LDS bounce ----------------
__global__ __launch_bounds__(128, 2) void qkv_gemm(const __bf16* __restrict__ xn,
                                                   const __bf16* __restrict__ wt,
                                                   const float* __restrict__ bq,
                                                   const float* __restrict__ bk,
                                                   const float* __restrict__ bv,
                                                   __bf16* __restrict__ qout,
                                                   __bf16* __restrict__ kout,
                                                   __bf16* __restrict__ vtout) {
    __shared__ __bf16 atile[64][264];
    int w = blockIdx.z;
    const __bf16* Wl = wt + (size_t)w * 65536;
    int tid = threadIdx.x;
    int wave = tid >> 6, lane = tid & 63;
    int quad = lane >> 4, l16 = lane & 15;
    int m0 = blockIdx.x * 64;
    int ntbase = blockIdx.y * 8 + wave * 4;

#pragma unroll
    for (int i = 0; i < 16; i++) {
        int c = tid + 128 * i;
        int row = c >> 5, col = (c & 31) * 8;
        *(bf16x8*)&atile[row][col] = *(const bf16x8*)(xn + (size_t)(m0 + row) * 256 + col);
    }
    bf16x8 bfr[4][8];
#pragma unroll
    for (int ct = 0; ct < 4; ct++)
#pragma unroll
        for (int kf = 0; kf < 8; kf++)
            bfr[ct][kf] = *(const bf16x8*)(Wl + ((((size_t)(ntbase + ct) * 8 + kf) * 4 + quad) * 16 + l16) * 8);
    __syncthreads();

    f32x4 acc[4][4];
#pragma unroll
    for (int mt = 0; mt < 4; mt++)
#pragma unroll
        for (int ct = 0; ct < 4; ct++)
#pragma unroll
            for (int r = 0; r < 4; r++) acc[mt][ct][r] = 0.f;
#pragma unroll
    for (int kf = 0; kf < 8; kf++) {
        bf16x8 af[4];
#pragma unroll
        for (int mt = 0; mt < 4; mt++)
            af[mt] = *(const bf16x8*)&atile[mt * 16 + l16][kf * 32 + quad * 8];
#pragma unroll
        for (int mt = 0; mt < 4; mt++)
#pragma unroll
            for (int ct = 0; ct < 4; ct++)
                acc[mt][ct] = MFMA16(af[mt], bfr[ct][kf], acc[mt][ct]);
    }

    if (w == 2) {
        // transposed store via LDS bounce (coalesced 16B stores)
        __syncthreads();   // all waves done reading atile
        __bf16 (*vtl)[70] = (__bf16(*)[70])atile;    // 128 c x (64 n + pad)
#pragma unroll
        for (int mt = 0; mt < 4; mt++) {
#pragma unroll
            for (int ct = 0; ct < 4; ct++) {
                int cl = (wave * 4 + ct) * 16 + l16;   // 0..127 block-local channel
                float bias_v = bv[blockIdx.y * 128 + cl];
                bf16x4 pv;
#pragma unroll
                for (int r = 0; r < 4; r++) pv[r] = (__bf16)(acc[mt][ct][r] + bias_v);
                *(bf16x4*)&vtl[cl][mt * 16 + quad * 4] = pv;
            }
        }
        __syncthreads();
        int bb = m0 >> 12, n0g = m0 & 4095;
#pragma unroll
        for (int j = 0; j < 8; j++) {
            int chunk = tid + 128 * j;          // 0..1023
            int cl = chunk >> 3, n8 = chunk & 7;
            *(bf16x8*)(vtout + ((size_t)(bb * 256 + blockIdx.y * 128 + cl)) * 4096 + n0g + n8 * 8)
                = *(const bf16x8*)&vtl[cl][n8 * 8];
        }
    } else {
        const float* bias = (w == 0) ? bq : bk;
        // q pre-scaled by (1/16)*log2(e) so flash softmax runs in exp2 domain
        const float qscale = 0.09016844f;
#pragma unroll
        for (int mt = 0; mt < 4; mt++) {
#pragma unroll
            for (int ct = 0; ct < 4; ct++) {
                int c = (ntbase + ct) * 16 + l16;
                float bias_v = bias[c];
#pragma unroll
                for (int r = 0; r < 4; r++) {
                    int m = m0 + mt * 16 + quad * 4 + r;
                    float val = acc[mt][ct][r] + bias_v;
                    if (w == 0) qout[(size_t)m * 256 + c] = (__bf16)(val * qscale);
                    else        kout[(size_t)m * 256 + c] = (__bf16)val;
                }
            }
        }
    }
}

// ---------------- Flash attention v10: software-pipelined QK^T (tile it+1) overlapped
// with softmax(it)+PV(it); raw s_barrier + counted vmcnt so K/V prefetch stays in
// flight across barriers.  VMEM issue order invariant per iter: [K gloads older,
// V reg-loads newer] -> V-commit's auto wait = vmcnt(4) (K survives); manual
// pre-barrier wait vmcnt(4) = K done (V survives across barrier).
__global__ __launch_bounds__(256, 2) void flash_attn(const __bf16* __restrict__ q,
                                                     const __bf16* __restrict__ k,
                                                     const __bf16* __restrict__ vt,
                                                     __bf16* __restrict__ po,
                                                     float* __restrict__ ml) {
    __shared__ __align__(16) char smem[69632];
    // K dbuf at smem+0 / +16384, unpadded, XOR-swizzled 16B chunks (cp holds cl = cp ^ row)
    __bf16 (*vtile0)[36] = (__bf16(*)[36])(smem + 32768);   // 18432 B
    __bf16 (*vtile1)[36] = (__bf16(*)[36])(smem + 51200);   // 18432 B
    __bf16 (*otr)[32][264] = (__bf16(*)[32][264])smem;      // epilogue overlay

    const int tid = threadIdx.x;
    const int wave = tid >> 6, lane = tid & 63;
    const int l32 = lane & 31, h = lane >> 5;
    // XCD-aware swizzle (T1): chunked remap, nwg=512 divisible by 8 -> bijective
    const int fid = blockIdx.x;
    const int cid = ((fid & 7) << 6) | (fid >> 3);
    const int qt  = cid & 31;
    const int ksb = cid >> 5;        // 0..15
    const int ks  = ksb & 3, b = ksb >> 2;
    const int row0 = qt * 128 + wave * 32;
    const size_t rowg0 = (size_t)b * 4096 + row0;

    const char*   kb = (const char*)(k + ((size_t)b * 4096 + ks * 1024) * 256);
    const __bf16* vb = vt + (size_t)b * 256 * 4096 + ks * 1024;

    int koff[4];
#pragma unroll
    for (int i = 0; i < 4; i++) {
        int P = wave * 256 + i * 64 + lane;
        int r = P >> 5, cp = P & 31;
        koff[i] = r * 512 + (cp ^ r) * 16;
    }
    const int kldsoff = wave * 4096;

    bf16x8 qf[16];
    const __bf16* qbase = q + (rowg0 + l32) * 256 + h * 8;
#pragma unroll
    for (int s = 0; s < 16; s++) qf[s] = *(const bf16x8*)(qbase + s * 16);

    f32x16 acc[8];
#pragma unroll
    for (int ct = 0; ct < 8; ct++)
#pragma unroll
        for (int r = 0; r < 16; r++) acc[ct][r] = 0.f;
    float mi = -1e30f, li = 0.f;

    // V staging: vb rows are channels 0..255; idx covers 256 ch x 4 chunks of 8 keys
    const int vr_ = tid >> 2, vc4 = tid & 3;
    bf16x8 vc[4];

    // ---- prologue: K(0)->buf0, V(0)->regs ----
#pragma unroll
    for (int i = 0; i < 4; i++)
        gload_lds16(kb + koff[i], smem + kldsoff + i * 1024);
#pragma unroll
    for (int i = 0; i < 4; i++)
        vc[i] = *(const bf16x8*)(vb + (size_t)(vr_ + 64 * i) * 4096 + vc4 * 8);
    asm volatile("s_waitcnt vmcnt(4)" ::: "memory");   // K(0) done; V(0) in flight
    __builtin_amdgcn_sched_barrier(0);
    __builtin_amdgcn_s_barrier();

    // ---- QK^T(0) -> (sA0, sA1) from buf0 ----
    f32x16 sA0, sA1, sB0, sB1;
#pragma unroll
    for (int r = 0; r < 16; r++) { sA0[r] = 0.f; sA1[r] = 0.f; }
#pragma unroll
    for (int kf = 0; kf < 8; kf++) {
        int cl = kf * 2 + h;
        bf16x8 ka = *(const bf16x8*)(smem + l32 * 512 + ((cl ^ l32) << 4));
        sA0 = MFMA32(ka, qf[kf], sA0);
    }
#pragma unroll
    for (int kf = 8; kf < 16; kf++) {
        int cl = kf * 2 + h;
        bf16x8 ka = *(const bf16x8*)(smem + l32 * 512 + ((cl ^ l32) << 4));
        sA1 = MFMA32(ka, qf[kf], sA1);
    }
    // commit V(0) -> vtile0 (compiler auto-waits the V(0) loads, counted)
#pragma unroll
    for (int i = 0; i < 4; i++)
        *(bf16x8*)&vtile0[vr_ + 64 * i][vc4 * 8] = vc[i];
    // stage K(1)->buf1 first, then V(1)->regs (order invariant: K older, V newer)
#pragma unroll
    for (int i = 0; i < 4; i++)
        gload_lds16(kb + 16384 + koff[i], smem + 16384 + kldsoff + i * 1024);
#pragma unroll
    for (int i = 0; i < 4; i++)
        vc[i] = *(const bf16x8*)(vb + (size_t)(vr_ + 64 * i) * 4096 + 32 + vc4 * 8);
    asm volatile("s_waitcnt vmcnt(4) lgkmcnt(0)" ::: "memory");  // K(1) done, commits visible
    __builtin_amdgcn_sched_barrier(0);
    __builtin_amdgcn_s_barrier();

// iteration body: PAR = it&1 (compile-time at each call site).
// SC = S-tile of key-tile it (pair of chains); SN = accumulators for tile it+1.
#define FA_BODY(IT, PAR, SC0, SC1, SN0, SN1)                                        \
  {                                                                                 \
    const int it_ = (IT);                                                           \
    /* stage K(it+2) -> kbuf[PAR] (buffer holding K(it), free since last barrier) */\
    if (it_ < 30) {                                                                 \
      const char* kg_ = kb + (size_t)(it_ + 2) * 16384;                             \
      char* kw_ = smem + ((PAR) ? 16384 : 0);                                       \
      _Pragma("unroll") for (int i = 0; i < 4; i++)                                 \
        gload_lds16(kg_ + koff[i], kw_ + kldsoff + i * 1024);                       \
    }                                                                               \
    /* QK^T(it+1) from kbuf[1-PAR] -> SN (2 independent chains) */                  \
    if (it_ < 31) {                                                                 \
      const char* kr_ = smem + ((PAR) ? 0 : 16384);                                 \
      _Pragma("unroll") for (int r = 0; r < 16; r++) { SN0[r] = 0.f; SN1[r] = 0.f; }\
      _Pragma("unroll") for (int kf = 0; kf < 8; kf++) {                            \
        int cl = kf * 2 + h;                                                        \
        bf16x8 ka = *(const bf16x8*)(kr_ + l32 * 512 + ((cl ^ l32) << 4));          \
        SN0 = MFMA32(ka, qf[kf], SN0);                                              \
      }                                                                             \
      _Pragma("unroll") for (int kf = 8; kf < 16; kf++) {                           \
        int cl = kf * 2 + h;                                                        \
        bf16x8 ka = *(const bf16x8*)(kr_ + l32 * 512 + ((cl ^ l32) << 4));          \
        SN1 = MFMA32(ka, qf[kf], SN1);                                              \
      }                                                                             \
    }                                                                               \
    /* softmax(it): pure VALU, independent of the QK^T(it+1) MFMAs above */         \
    f32x16 s_;                                                                      \
    _Pragma("unroll") for (int r = 0; r < 16; r++) s_[r] = SC0[r] + SC1[r];         \
    float mx = s_[0];                                                               \
    _Pragma("unroll") for (int r = 1; r < 16; r++) mx = fmaxf(mx, s_[r]);           \
    mx = fmaxf(mx, __shfl_xor(mx, 32));                                             \
    if (__ballot(mx > mi + 8.0f)) {                                                 \
      float mnew = fmaxf(mi, mx);                                                   \
      float alpha = exp2f(mi - mnew);                                               \
      _Pragma("unroll") for (int ct = 0; ct < 8; ct++)                              \
        _Pragma("unroll") for (int r = 0; r < 16; r++) acc[ct][r] *= alpha;         \
      li *= alpha;                                                                  \
      mi = mnew;                                                                    \
    }                                                                               \
    float rs = 0.f;                                                                 \
    _Pragma("unroll") for (int r = 0; r < 16; r++) {                                \
      float p = exp2f(s_[r] - mi); s_[r] = p; rs += p; }                            \
    rs += __shfl_xor(rs, 32);                                                       \
    li += rs;                                                                       \
    bf16x8 pf0, pf1;                                                                \
    _Pragma("unroll") for (int j = 0; j < 8; j++) {                                 \
      pf0[j] = (__bf16)s_[j]; pf1[j] = (__bf16)s_[8 + j]; }                         \
    /* commit vc = V(it+1) -> vbuf[1-PAR]; auto-wait = counted vmcnt(4) */          \
    if (it_ < 31) {                                                                 \
      __bf16 (*vn_)[36] = (PAR) ? vtile0 : vtile1;                                  \
      _Pragma("unroll") for (int i = 0; i < 4; i++)                                 \
        *(bf16x8*)&vn_[vr_ + 64 * i][vc4 * 8] = vc[i];                              \
    }                                                                               \
    /* reload vc = V(it+2) (issued after K(it+2): keeps [K old, V new] order) */    \
    if (it_ < 30) {                                                                 \
      const int kn_ = (it_ + 2) * 32;                                               \
      _Pragma("unroll") for (int i = 0; i < 4; i++)                                 \
        vc[i] = *(const bf16x8*)(vb + (size_t)(vr_ + 64 * i) * 4096 + kn_ + vc4 * 8);\
    }                                                                               \
    /* PV(it) from vbuf[PAR] */                                                     \
    {                                                                               \
      __bf16 (*vc_)[36] = (PAR) ? vtile1 : vtile0;                                  \
      __builtin_amdgcn_s_setprio(1);                                                \
      _Pragma("unroll") for (int ct = 0; ct < 8; ct++) {                            \
        const __bf16* vr2 = &vc_[ct * 32 + l32][0];                                 \
        bf16x4 a00 = *(const bf16x4*)(vr2 + 4 * h);                                 \
        bf16x4 a01 = *(const bf16x4*)(vr2 + 8 + 4 * h);                             \
        bf16x8 va0 = __builtin_shufflevector(a00, a01, 0, 1, 2, 3, 4, 5, 6, 7);     \
        acc[ct] = MFMA32(va0, pf0, acc[ct]);                                        \
        bf16x4 a10 = *(const bf16x4*)(vr2 + 16 + 4 * h);                            \
        bf16x4 a11 = *(const bf16x4*)(vr2 + 24 + 4 * h);                            \
        bf16x8 va1 = __builtin_shufflevector(a10, a11, 0, 1, 2, 3, 4, 5, 6, 7);     \
        acc[ct] = MFMA32(va1, pf1, acc[ct]);                                        \
      }                                                                             \
      __builtin_amdgcn_s_setprio(0);                                                \
    }                                                                               \
    /* K(it+2) done before barrier (cross-wave); V(it+2) stays in flight */         \
    asm volatile("s_waitcnt vmcnt(4) lgkmcnt(0)" ::: "memory");                     \
    __builtin_amdgcn_sched_barrier(0);                                              \
    __builtin_amdgcn_s_barrier();                                                   \
  }

    for (int i2 = 0; i2 < 16; ++i2) {
        FA_BODY(2 * i2,     0, sA0, sA1, sB0, sB1);
        FA_BODY(2 * i2 + 1, 1, sB0, sB1, sA0, sA1);
    }
#undef FA_BODY

    // epilogue: transpose O^T -> row-major via wave-private LDS region
    // (final body ended with full waits + barrier -> smem overlay safe)
#pragma unroll
    for (int ct = 0; ct < 8; ct++) {
#pragma unroll
        for (int pk = 0; pk < 4; pk++) {
            bf16x4 op;
            op[0] = (__bf16)acc[ct][pk * 4];     op[1] = (__bf16)acc[ct][pk * 4 + 1];
            op[2] = (__bf16)acc[ct][pk * 4 + 2]; op[3] = (__bf16)acc[ct][pk * 4 + 3];
            *(bf16x4*)&otr[wave][l32][ct * 32 + pk * 8 + h * 4] = op;
        }
    }
    if (lane < 32) {
        float2 v; v.x = mi; v.y = li;    // mi in log2 domain
        *(float2*)&ml[((size_t)ks * 16384 + rowg0 + l32) * 2] = v;
    }
    __syncthreads();
    __bf16* pobase = po + ((size_t)ks * 16384 + rowg0) * 256;
    const int rr = lane >> 1, half = lane & 1;
#pragma unroll
    for (int j = 0; j < 16; j++) {
        bf16x8 val = *(const bf16x8*)&otr[wave][rr][half * 128 + j * 8];
        *(bf16x8*)(pobase + (size_t)rr * 256 + half * 128 + j * 8) = val;
    }
}

// ---------------- Projection GEMM + fused 4-way merge + bias + residual ----------------
__global__ __launch_bounds__(128, 2) void proj_gemm(const __bf16* __restrict__ po,
                                                    const float* __restrict__ ml,
                                                    const __bf16* __restrict__ wpl,
                                                    const float* __restrict__ bp,
                                                    float* __restrict__ out) {
    __shared__ __bf16 atile[64][264];
    int tid = threadIdx.x;
    int wave = tid >> 6, lane = tid & 63;
    int quad = lane >> 4, l16 = lane & 15;
    int m0 = blockIdx.x * 64;
    int ntbase = blockIdx.y * 8 + wave * 4;

    // stage A-tile = merged attention output (4 key-split partials, exp2 domain)
#pragma unroll
    for (int i = 0; i < 16; i++) {
        int c = tid + 128 * i;
        int row = c >> 5, col8 = c & 31;
        int m = m0 + row;
        float mm[4], ll[4];
#pragma unroll
        for (int s = 0; s < 4; s++) {
            float2 v = *(const float2*)&ml[((size_t)s * 16384 + m) * 2];
            mm[s] = v.x; ll[s] = v.y;
        }
        float M = fmaxf(fmaxf(mm[0], mm[1]), fmaxf(mm[2], mm[3]));
        float den = 0.f, w[4];
#pragma unroll
        for (int s = 0; s < 4; s++) { w[s] = exp2f(mm[s] - M); den += ll[s] * w[s]; }
        float accv[8];
#pragma unroll
        for (int e = 0; e < 8; e++) accv[e] = 0.f;
#pragma unroll
        for (int s = 0; s < 4; s++) {
            bf16x8 pv = *(const bf16x8*)(po + ((size_t)s * 16384 + m) * 256 + col8 * 8);
#pragma unroll
            for (int e = 0; e < 8; e++) accv[e] += w[s] * (float)pv[e];
        }
        float rinv = 1.f / den;
        bf16x8 o;
#pragma unroll
        for (int e = 0; e < 8; e++) o[e] = (__bf16)(accv[e] * rinv);
        *(bf16x8*)&atile[row][col8 * 8] = o;
    }
    bf16x8 bfr[4][8];
#pragma unroll
    for (int ct = 0; ct < 4; ct++)
#pragma unroll
        for (int kf = 0; kf < 8; kf++)
            bfr[ct][kf] = *(const bf16x8*)(wpl + ((((size_t)(ntbase + ct) * 8 + kf) * 4 + quad) * 16 + l16) * 8);
    __syncthreads();

    f32x4 acc[4][4];
#pragma unroll
    for (int mt = 0; mt < 4; mt++)
#pragma unroll
        for (int ct = 0; ct < 4; ct++)
#pragma unroll
            for (int r = 0; r < 4; r++) acc[mt][ct][r] = 0.f;
#pragma unroll
    for (int kf = 0; kf < 8; kf++) {
        bf16x8 af[4];
#pragma unroll
        for (int mt = 0; mt < 4; mt++)
            af[mt] = *(const bf16x8*)&atile[mt * 16 + l16][kf * 32 + quad * 8];
#pragma unroll
        for (int mt = 0; mt < 4; mt++)
#pragma unroll
            for (int ct = 0; ct < 4; ct++)
                acc[mt][ct] = MFMA16(af[mt], bfr[ct][kf], acc[mt][ct]);
    }
#pragma unroll
    for (int mt = 0; mt < 4; mt++) {
#pragma unroll
        for (int ct = 0; ct < 4; ct++) {
            int c = (ntbase + ct) * 16 + l16;
            float bias_v = bp[c];
#pragma unroll
            for (int r = 0; r < 4; r++) {
                int m = m0 + mt * 16 + quad * 4 + r;
                size_t idx = (size_t)m * 256 + c;
                out[idx] = out[idx] + acc[mt][ct][r] + bias_v;
            }
        }
    }
}

extern "C" void kernel_launch(void* const* d_in, const int* in_sizes, int n_in,
                              void* d_out, int out_size, void* d_ws, size_t ws_size,
                              hipStream_t stream) {
    const float* x     = (const float*)d_in[0];
    const float* gamma = (const float*)d_in[1];
    const float* beta  = (const float*)d_in[2];
    const float* Wq    = (const float*)d_in[3];
    const float* bq    = (const float*)d_in[4];
    const float* Wk    = (const float*)d_in[5];
    const float* bk    = (const float*)d_in[6];
    const float* Wv    = (const float*)d_in[7];
    const float* bv    = (const float*)d_in[8];
    const float* Wp    = (const float*)d_in[9];
    const float* bp    = (const float*)d_in[10];
    float* out = (float*)d_out;

    char* ws = (char*)d_ws;
    __bf16* xn_bf   = (__bf16*)(ws);                    //  8,388,608 B
    __bf16* wt      = (__bf16*)(ws + 8388608);          //    524,288 B (fragment-linear)
    __bf16* qbuf    = (__bf16*)(ws + 8912896);          //  8,388,608 B
    __bf16* kbuf    = (__bf16*)(ws + 17301504);         //  8,388,608 B
    __bf16* vtbuf   = (__bf16*)(ws + 25690112);         //  8,388,608 B
    __bf16* po      = (__bf16*)(ws + 34078720);         // 33,554,432 B
    float*  ml      = (float*)(ws + 67633152);          //    524,288 B
    float*  pstats  = (float*)(ws + 68157440);          //      4,096 B
    float*  gstats  = (float*)(ws + 68161536);          //        256 B

    gn_stats1<<<512, 256, 0, stream>>>(x, pstats);
    gn_stats2<<<1, 64, 0, stream>>>(pstats, gstats);
    gn_norm<<<4096, 256, 0, stream>>>(x, gamma, beta, gstats, out, xn_bf);
    prep_w<<<1024, 256, 0, stream>>>(Wq, Wk, Wv, Wp, wt);
    qkv_gemm<<<dim3(256, 2, 3), 128, 0, stream>>>(xn_bf, wt, bq, bk, bv, qbuf, kbuf, vtbuf);
    flash_attn<<<512, 256, 0, stream>>>(qbuf, kbuf, vtbuf, po, ml);
    proj_gemm<<<dim3(256, 2), 128, 0, stream>>>(po, ml, wt + 3 * 65536, bp, out);
}

// Round 3
// 272.967 us; speedup vs baseline: 1.4638x; 1.4638x over previous
//
#include <hip/hip_runtime.h>
#include <hip/hip_bf16.h>

typedef __bf16 bf16x8 __attribute__((ext_vector_type(8)));
typedef __bf16 bf16x4 __attribute__((ext_vector_type(4)));
typedef float f32x4 __attribute__((ext_vector_type(4)));
typedef float f32x16 __attribute__((ext_vector_type(16)));

#define MFMA16(a,b,c) __builtin_amdgcn_mfma_f32_16x16x32_bf16((a),(b),(c),0,0,0)
#define MFMA32(a,b,c) __builtin_amdgcn_mfma_f32_32x32x16_bf16((a),(b),(c),0,0,0)

// async global->LDS, 16B per lane; lds dst = wave-uniform base + lane*16
__device__ __forceinline__ void gload_lds16(const void* g, void* l) {
    __builtin_amdgcn_global_load_lds((const __attribute__((address_space(1))) unsigned int*)g,
                                     (__attribute__((address_space(3))) unsigned int*)l, 16, 0, 0);
}

// ---------------- GroupNorm stats, stage 1 ----------------
__global__ __launch_bounds__(256) void gn_stats1(const float* __restrict__ x,
                                                 float* __restrict__ pstats) {
    int blk = blockIdx.x;            // 0..511
    int bg = blk >> 4, sl = blk & 15;
    int b = bg >> 3, g = bg & 7;
    const float* base = x + ((size_t)b * 4096 + sl * 256) * 256 + g * 32;
    float s = 0.f, s2 = 0.f;
    for (int i = threadIdx.x; i < 2048; i += 256) {
        int pos = i >> 3, f4 = i & 7;
        float4 v = *(const float4*)(base + (size_t)pos * 256 + f4 * 4);
        s  += v.x + v.y + v.z + v.w;
        s2 += v.x * v.x + v.y * v.y + v.z * v.z + v.w * v.w;
    }
    for (int off = 32; off; off >>= 1) {
        s  += __shfl_down(s, off);
        s2 += __shfl_down(s2, off);
    }
    __shared__ float red[8];
    int wave = threadIdx.x >> 6, lane = threadIdx.x & 63;
    if (lane == 0) { red[wave] = s; red[4 + wave] = s2; }
    __syncthreads();
    if (threadIdx.x == 0) {
        pstats[blk * 2]     = red[0] + red[1] + red[2] + red[3];
        pstats[blk * 2 + 1] = red[4] + red[5] + red[6] + red[7];
    }
}

// ---------------- GroupNorm stats, stage 2 ----------------
__global__ void gn_stats2(const float* __restrict__ pstats, float* __restrict__ stats) {
    int bg = threadIdx.x;
    if (bg < 32) {
        float S = 0.f, S2 = 0.f;
        for (int sl = 0; sl < 16; sl++) {
            S  += pstats[(bg * 16 + sl) * 2];
            S2 += pstats[(bg * 16 + sl) * 2 + 1];
        }
        const float invN = 1.f / 131072.f;
        float mean = S * invN;
        float var = S2 * invN - mean * mean;
        stats[bg * 2] = mean;
        stats[bg * 2 + 1] = rsqrtf(var + 1e-3f);
    }
}

// ---------------- GroupNorm normalize ----------------
__global__ __launch_bounds__(256) void gn_norm(const float* __restrict__ x,
                                               const float* __restrict__ gamma,
                                               const float* __restrict__ beta,
                                               const float* __restrict__ stats,
                                               float* __restrict__ xn_f32,
                                               __bf16* __restrict__ xn_bf) {
    size_t idx = (size_t)blockIdx.x * 256 + threadIdx.x;
    int c4 = (int)(idx & 63);
    int row = (int)(idx >> 6);
    int b = row >> 12;
    int g = c4 >> 3;
    float mean = stats[(b * 8 + g) * 2];
    float rstd = stats[(b * 8 + g) * 2 + 1];
    float4 xv = ((const float4*)x)[idx];
    float4 ga = ((const float4*)gamma)[c4];
    float4 be = ((const float4*)beta)[c4];
    float4 r;
    r.x = (xv.x - mean) * rstd * ga.x + be.x;
    r.y = (xv.y - mean) * rstd * ga.y + be.y;
    r.z = (xv.z - mean) * rstd * ga.z + be.z;
    r.w = (xv.w - mean) * rstd * ga.w + be.w;
    ((float4*)xn_f32)[idx] = r;
    bf16x4 o;
    o[0] = (__bf16)r.x; o[1] = (__bf16)r.y; o[2] = (__bf16)r.z; o[3] = (__bf16)r.w;
    *(bf16x4*)(xn_bf + idx * 4) = o;
}

// ---------------- Weight prep: fp32 [k][n] -> bf16 fragment-linear ----------------
__global__ __launch_bounds__(256) void prep_w(const float* __restrict__ Wq,
                                              const float* __restrict__ Wk,
                                              const float* __restrict__ Wv,
                                              const float* __restrict__ Wp,
                                              __bf16* __restrict__ wt) {
    int o = blockIdx.x * 256 + threadIdx.x;  // 0..262143
    int w = o >> 16;
    int rem = o & 65535;
    int nt   = rem >> 12;
    int kf   = (rem >> 9) & 7;
    int quad = (rem >> 7) & 3;
    int l16  = (rem >> 3) & 15;
    int j    = rem & 7;
    int n = nt * 16 + l16;
    int k = kf * 32 + quad * 8 + j;
    const float* W = (w == 0) ? Wq : (w == 1) ? Wk : (w == 2) ? Wv : Wp;
    wt[o] = (__bf16)W[k * 256 + n];
}

// ---------------- QKV GEMM: LDS A-tile; v stored transposed via LDS bounce ----------------
__global__ __launch_bounds__(128, 2) void qkv_gemm(const __bf16* __restrict__ xn,
                                                   const __bf16* __restrict__ wt,
                                                   const float* __restrict__ bq,
                                                   const float* __restrict__ bk,
                                                   const float* __restrict__ bv,
                                                   __bf16* __restrict__ qout,
                                                   __bf16* __restrict__ kout,
                                                   __bf16* __restrict__ vtout) {
    __shared__ __bf16 atile[64][264];
    int w = blockIdx.z;
    const __bf16* Wl = wt + (size_t)w * 65536;
    int tid = threadIdx.x;
    int wave = tid >> 6, lane = tid & 63;
    int quad = lane >> 4, l16 = lane & 15;
    int m0 = blockIdx.x * 64;
    int ntbase = blockIdx.y * 8 + wave * 4;

#pragma unroll
    for (int i = 0; i < 16; i++) {
        int c = tid + 128 * i;
        int row = c >> 5, col = (c & 31) * 8;
        *(bf16x8*)&atile[row][col] = *(const bf16x8*)(xn + (size_t)(m0 + row) * 256 + col);
    }
    bf16x8 bfr[4][8];
#pragma unroll
    for (int ct = 0; ct < 4; ct++)
#pragma unroll
        for (int kf = 0; kf < 8; kf++)
            bfr[ct][kf] = *(const bf16x8*)(Wl + ((((size_t)(ntbase + ct) * 8 + kf) * 4 + quad) * 16 + l16) * 8);
    __syncthreads();

    f32x4 acc[4][4];
#pragma unroll
    for (int mt = 0; mt < 4; mt++)
#pragma unroll
        for (int ct = 0; ct < 4; ct++)
#pragma unroll
            for (int r = 0; r < 4; r++) acc[mt][ct][r] = 0.f;
#pragma unroll
    for (int kf = 0; kf < 8; kf++) {
        bf16x8 af[4];
#pragma unroll
        for (int mt = 0; mt < 4; mt++)
            af[mt] = *(const bf16x8*)&atile[mt * 16 + l16][kf * 32 + quad * 8];
#pragma unroll
        for (int mt = 0; mt < 4; mt++)
#pragma unroll
            for (int ct = 0; ct < 4; ct++)
                acc[mt][ct] = MFMA16(af[mt], bfr[ct][kf], acc[mt][ct]);
    }

    if (w == 2) {
        // transposed store via LDS bounce (coalesced 16B stores)
        __syncthreads();   // all waves done reading atile
        __bf16 (*vtl)[70] = (__bf16(*)[70])atile;    // 128 c x (64 n + pad)
#pragma unroll
        for (int mt = 0; mt < 4; mt++) {
#pragma unroll
            for (int ct = 0; ct < 4; ct++) {
                int cl = (wave * 4 + ct) * 16 + l16;   // 0..127 block-local channel
                float bias_v = bv[blockIdx.y * 128 + cl];
                bf16x4 pv;
#pragma unroll
                for (int r = 0; r < 4; r++) pv[r] = (__bf16)(acc[mt][ct][r] + bias_v);
                *(bf16x4*)&vtl[cl][mt * 16 + quad * 4] = pv;
            }
        }
        __syncthreads();
        int bb = m0 >> 12, n0g = m0 & 4095;
#pragma unroll
        for (int j = 0; j < 8; j++) {
            int chunk = tid + 128 * j;          // 0..1023
            int cl = chunk >> 3, n8 = chunk & 7;
            *(bf16x8*)(vtout + ((size_t)(bb * 256 + blockIdx.y * 128 + cl)) * 4096 + n0g + n8 * 8)
                = *(const bf16x8*)&vtl[cl][n8 * 8];
        }
    } else {
        const float* bias = (w == 0) ? bq : bk;
        // q pre-scaled by (1/16)*log2(e) so flash softmax runs in exp2 domain
        const float qscale = 0.09016844f;
#pragma unroll
        for (int mt = 0; mt < 4; mt++) {
#pragma unroll
            for (int ct = 0; ct < 4; ct++) {
                int c = (ntbase + ct) * 16 + l16;
                float bias_v = bias[c];
#pragma unroll
                for (int r = 0; r < 4; r++) {
                    int m = m0 + mt * 16 + quad * 4 + r;
                    float val = acc[mt][ct][r] + bias_v;
                    if (w == 0) qout[(size_t)m * 256 + c] = (__bf16)(val * qscale);
                    else        kout[(size_t)m * 256 + c] = (__bf16)val;
                }
            }
        }
    }
}

// ---------------- Flash attention v11: deferred-PV pipeline, zero extra f32 state ----
// PV(it-1) (using persisted bf16 pf fragments, 8 regs) is hand-zipped 1:1 with the
// QK^T(it) MFMA chain -> two independent chains feed the matrix pipe.  Rescale reads
// acc so it orders after PV automatically.  One barrier/iter; V(it) commits at
// iteration start (loads a full iteration old); K(it+1) stages into the buffer freed
// two barriers ago; pre-barrier wait = counted vmcnt(4) (V prefetch stays in flight).
__global__ __launch_bounds__(256, 2) void flash_attn(const __bf16* __restrict__ q,
                                                     const __bf16* __restrict__ k,
                                                     const __bf16* __restrict__ vt,
                                                     __bf16* __restrict__ po,
                                                     float* __restrict__ ml) {
    __shared__ __align__(16) char smem[69632];
    // K dbuf at smem+0 / +16384, unpadded, XOR-swizzled 16B chunks (cp holds cl = cp ^ row)
    __bf16 (*vtile0)[36] = (__bf16(*)[36])(smem + 32768);   // 18432 B
    __bf16 (*vtile1)[36] = (__bf16(*)[36])(smem + 51200);   // 18432 B
    __bf16 (*otr)[32][264] = (__bf16(*)[32][264])smem;      // epilogue overlay

    const int tid = threadIdx.x;
    const int wave = tid >> 6, lane = tid & 63;
    const int l32 = lane & 31, h = lane >> 5;
    // XCD-aware swizzle (T1): chunked remap, nwg=512 divisible by 8 -> bijective
    const int fid = blockIdx.x;
    const int cid = ((fid & 7) << 6) | (fid >> 3);
    const int qt  = cid & 31;
    const int ksb = cid >> 5;        // 0..15
    const int ks  = ksb & 3, b = ksb >> 2;
    const int row0 = qt * 128 + wave * 32;
    const size_t rowg0 = (size_t)b * 4096 + row0;

    const char*   kb = (const char*)(k + ((size_t)b * 4096 + ks * 1024) * 256);
    const __bf16* vb = vt + (size_t)b * 256 * 4096 + ks * 1024;

    int koff[4];
#pragma unroll
    for (int i = 0; i < 4; i++) {
        int P = wave * 256 + i * 64 + lane;
        int r = P >> 5, cp = P & 31;
        koff[i] = r * 512 + (cp ^ r) * 16;
    }
    const int kldsoff = wave * 4096;

    bf16x8 qf[16];
    const __bf16* qbase = q + (rowg0 + l32) * 256 + h * 8;
#pragma unroll
    for (int s = 0; s < 16; s++) qf[s] = *(const bf16x8*)(qbase + s * 16);

    f32x16 acc[8];
#pragma unroll
    for (int ct = 0; ct < 8; ct++)
#pragma unroll
        for (int r = 0; r < 16; r++) acc[ct][r] = 0.f;
    float mi = -1e30f, li = 0.f;

    // V staging: vb rows are channels 0..255; lane covers ch vr_, key-chunk vc4
    const int vr_ = tid >> 2, vc4 = tid & 3;
    bf16x8 vc[4];
    bf16x8 pf0, pf1;

    // ---- prologue: K(0)->kbuf0, V(0)->regs, K(1)->kbuf1 ----
#pragma unroll
    for (int i = 0; i < 4; i++)
        gload_lds16(kb + koff[i], smem + kldsoff + i * 1024);
#pragma unroll
    for (int i = 0; i < 4; i++)
        vc[i] = *(const bf16x8*)(vb + (size_t)(vr_ + 64 * i) * 4096 + vc4 * 8);
#pragma unroll
    for (int i = 0; i < 4; i++)
        gload_lds16(kb + 16384 + koff[i], smem + 16384 + kldsoff + i * 1024);
    asm volatile("s_waitcnt vmcnt(8)" ::: "memory");   // K(0) landed; V(0)/K(1) in flight
    __builtin_amdgcn_sched_barrier(0);
    __builtin_amdgcn_s_barrier();

    // ---- it = 0: QK^T(0) chain + softmax -> pf(0); commit V(0); load V(1) ----
    {
        f32x16 s_;
#pragma unroll
        for (int r = 0; r < 16; r++) s_[r] = 0.f;
#pragma unroll
        for (int kf = 0; kf < 16; kf++) {
            int cl = kf * 2 + h;
            bf16x8 ka = *(const bf16x8*)(smem + l32 * 512 + ((cl ^ l32) << 4));
            s_ = MFMA32(ka, qf[kf], s_);
        }
        float mx = s_[0];
#pragma unroll
        for (int r = 1; r < 16; r++) mx = fmaxf(mx, s_[r]);
        mx = fmaxf(mx, __shfl_xor(mx, 32));
        mi = mx;                                  // first tile: no rescale needed
        float rs = 0.f;
#pragma unroll
        for (int r = 0; r < 16; r++) { float p = exp2f(s_[r] - mi); s_[r] = p; rs += p; }
        rs += __shfl_xor(rs, 32);
        li = rs;
#pragma unroll
        for (int j = 0; j < 8; j++) { pf0[j] = (__bf16)s_[j]; pf1[j] = (__bf16)s_[8 + j]; }
        // commit V(0) -> vtile0 (auto-wait: counted, K(1) stays in flight)
#pragma unroll
        for (int i = 0; i < 4; i++)
            *(bf16x8*)&vtile0[vr_ + 64 * i][vc4 * 8] = vc[i];
        // load vc = V(1)
#pragma unroll
        for (int i = 0; i < 4; i++)
            vc[i] = *(const bf16x8*)(vb + (size_t)(vr_ + 64 * i) * 4096 + 32 + vc4 * 8);
    }
    asm volatile("s_waitcnt vmcnt(4) lgkmcnt(0)" ::: "memory");  // K(1) done, V(0) commit visible
    __builtin_amdgcn_sched_barrier(0);
    __builtin_amdgcn_s_barrier();

// iteration body for it = 1..31.  PAR = it&1 (compile-time per call site).
// kbuf[PAR] = K(it) read; kbuf[1-PAR] = stage target K(it+1).
// vbuf[PAR] = commit target V(it); vbuf[1-PAR] = PV(it-1) source.
#define FA_BODY(IT, PAR, STAGE)                                                     \
  {                                                                                 \
    const int it_ = (IT);                                                           \
    /* 1. commit vc = V(it) -> vbuf[PAR] (vc loads are one iteration old) */        \
    { __bf16 (*vw_)[36] = (PAR) ? vtile1 : vtile0;                                  \
      _Pragma("unroll") for (int i = 0; i < 4; i++)                                 \
        *(bf16x8*)&vw_[vr_ + 64 * i][vc4 * 8] = vc[i]; }                            \
    /* 2. stage K(it+1) -> kbuf[1-PAR] (freed two barriers ago) */                  \
    if (STAGE) {                                                                    \
      const char* kg_ = kb + (size_t)(it_ + 1) * 16384;                             \
      char* kw_ = smem + ((PAR) ? 0 : 16384);                                       \
      _Pragma("unroll") for (int i = 0; i < 4; i++)                                 \
        gload_lds16(kg_ + koff[i], kw_ + kldsoff + i * 1024);                       \
      /* 3. vc = V(it+1) (issued after K: [K older, V newer] invariant) */          \
      const int kn_ = (it_ + 1) * 32;                                               \
      _Pragma("unroll") for (int i = 0; i < 4; i++)                                 \
        vc[i] = *(const bf16x8*)(vb + (size_t)(vr_ + 64 * i) * 4096 + kn_ + vc4 * 8);\
    }                                                                               \
    /* 4. QK^T(it) zipped 1:1 with PV(it-1): two independent MFMA chains */         \
    {                                                                               \
      const char* kr_ = smem + ((PAR) ? 16384 : 0);                                 \
      __bf16 (*vp_)[36] = (PAR) ? vtile0 : vtile1;                                  \
      f32x16 s_;                                                                    \
      _Pragma("unroll") for (int r = 0; r < 16; r++) s_[r] = 0.f;                   \
      __builtin_amdgcn_s_setprio(1);                                                \
      _Pragma("unroll") for (int u = 0; u < 8; u++) {                               \
        { int cl = (2 * u) * 2 + h;                                                 \
          bf16x8 ka = *(const bf16x8*)(kr_ + l32 * 512 + ((cl ^ l32) << 4));        \
          s_ = MFMA32(ka, qf[2 * u], s_); }                                         \
        { int cl = (2 * u + 1) * 2 + h;                                             \
          bf16x8 ka = *(const bf16x8*)(kr_ + l32 * 512 + ((cl ^ l32) << 4));        \
          s_ = MFMA32(ka, qf[2 * u + 1], s_); }                                     \
        { const __bf16* vr2 = &vp_[u * 32 + l32][0];                                \
          bf16x4 a00 = *(const bf16x4*)(vr2 + 4 * h);                               \
          bf16x4 a01 = *(const bf16x4*)(vr2 + 8 + 4 * h);                           \
          bf16x8 va0 = __builtin_shufflevector(a00, a01, 0, 1, 2, 3, 4, 5, 6, 7);   \
          acc[u] = MFMA32(va0, pf0, acc[u]);                                        \
          bf16x4 a10 = *(const bf16x4*)(vr2 + 16 + 4 * h);                          \
          bf16x4 a11 = *(const bf16x4*)(vr2 + 24 + 4 * h);                          \
          bf16x8 va1 = __builtin_shufflevector(a10, a11, 0, 1, 2, 3, 4, 5, 6, 7);   \
          acc[u] = MFMA32(va1, pf1, acc[u]);                                        \
        }                                                                           \
      }                                                                             \
      __builtin_amdgcn_s_setprio(0);                                                \
      /* softmax(it); acc-rescale reads acc -> ordered after PV(it-1) */            \
      float mx = s_[0];                                                             \
      _Pragma("unroll") for (int r = 1; r < 16; r++) mx = fmaxf(mx, s_[r]);         \
      mx = fmaxf(mx, __shfl_xor(mx, 32));                                           \
      if (__ballot(mx > mi + 8.0f)) {                                               \
        float mnew = fmaxf(mi, mx);                                                 \
        float alpha = exp2f(mi - mnew);                                             \
        _Pragma("unroll") for (int ct = 0; ct < 8; ct++)                            \
          _Pragma("unroll") for (int r = 0; r < 16; r++) acc[ct][r] *= alpha;       \
        li *= alpha; mi = mnew;                                                     \
      }                                                                             \
      float rs = 0.f;                                                               \
      _Pragma("unroll") for (int r = 0; r < 16; r++) {                              \
        float p = exp2f(s_[r] - mi); s_[r] = p; rs += p; }                          \
      rs += __shfl_xor(rs, 32);                                                     \
      li += rs;                                                                     \
      _Pragma("unroll") for (int j = 0; j < 8; j++) {                               \
        pf0[j] = (__bf16)s_[j]; pf1[j] = (__bf16)s_[8 + j]; }                       \
    }                                                                               \
    /* 5. K(it+1) done before barrier; V(it+1) stays in flight across it */         \
    if (STAGE) { asm volatile("s_waitcnt vmcnt(4) lgkmcnt(0)" ::: "memory"); }      \
    else       { asm volatile("s_waitcnt lgkmcnt(0)" ::: "memory"); }               \
    __builtin_amdgcn_sched_barrier(0);                                              \
    __builtin_amdgcn_s_barrier();                                                   \
  }

    for (int i2 = 0; i2 < 15; ++i2) {
        FA_BODY(2 * i2 + 1, 1, 1);
        FA_BODY(2 * i2 + 2, 0, 1);
    }
    FA_BODY(31, 1, 0);
#undef FA_BODY

    // ---- epilogue: final deferred PV(31) from vtile1 with pf(31) ----
#pragma unroll
    for (int u = 0; u < 8; u++) {
        const __bf16* vr2 = &vtile1[u * 32 + l32][0];
        bf16x4 a00 = *(const bf16x4*)(vr2 + 4 * h);
        bf16x4 a01 = *(const bf16x4*)(vr2 + 8 + 4 * h);
        bf16x8 va0 = __builtin_shufflevector(a00, a01, 0, 1, 2, 3, 4, 5, 6, 7);
        acc[u] = MFMA32(va0, pf0, acc[u]);
        bf16x4 a10 = *(const bf16x4*)(vr2 + 16 + 4 * h);
        bf16x4 a11 = *(const bf16x4*)(vr2 + 24 + 4 * h);
        bf16x8 va1 = __builtin_shufflevector(a10, a11, 0, 1, 2, 3, 4, 5, 6, 7);
        acc[u] = MFMA32(va1, pf1, acc[u]);
    }
    __syncthreads();   // all waves done reading vtile1 before otr overlay

    // transpose O^T -> row-major via wave-private LDS region
#pragma unroll
    for (int ct = 0; ct < 8; ct++) {
#pragma unroll
        for (int pk = 0; pk < 4; pk++) {
            bf16x4 op;
            op[0] = (__bf16)acc[ct][pk * 4];     op[1] = (__bf16)acc[ct][pk * 4 + 1];
            op[2] = (__bf16)acc[ct][pk * 4 + 2]; op[3] = (__bf16)acc[ct][pk * 4 + 3];
            *(bf16x4*)&otr[wave][l32][ct * 32 + pk * 8 + h * 4] = op;
        }
    }
    if (lane < 32) {
        float2 v; v.x = mi; v.y = li;    // mi in log2 domain
        *(float2*)&ml[((size_t)ks * 16384 + rowg0 + l32) * 2] = v;
    }
    __syncthreads();
    __bf16* pobase = po + ((size_t)ks * 16384 + rowg0) * 256;
    const int rr = lane >> 1, half = lane & 1;
#pragma unroll
    for (int j = 0; j < 16; j++) {
        bf16x8 val = *(const bf16x8*)&otr[wave][rr][half * 128 + j * 8];
        *(bf16x8*)(pobase + (size_t)rr * 256 + half * 128 + j * 8) = val;
    }
}

// ---------------- Projection GEMM + fused 4-way merge + bias + residual ----------------
__global__ __launch_bounds__(128, 2) void proj_gemm(const __bf16* __restrict__ po,
                                                    const float* __restrict__ ml,
                                                    const __bf16* __restrict__ wpl,
                                                    const float* __restrict__ bp,
                                                    float* __restrict__ out) {
    __shared__ __bf16 atile[64][264];
    int tid = threadIdx.x;
    int wave = tid >> 6, lane = tid & 63;
    int quad = lane >> 4, l16 = lane & 15;
    int m0 = blockIdx.x * 64;
    int ntbase = blockIdx.y * 8 + wave * 4;

    // stage A-tile = merged attention output (4 key-split partials, exp2 domain)
#pragma unroll
    for (int i = 0; i < 16; i++) {
        int c = tid + 128 * i;
        int row = c >> 5, col8 = c & 31;
        int m = m0 + row;
        float mm[4], ll[4];
#pragma unroll
        for (int s = 0; s < 4; s++) {
            float2 v = *(const float2*)&ml[((size_t)s * 16384 + m) * 2];
            mm[s] = v.x; ll[s] = v.y;
        }
        float M = fmaxf(fmaxf(mm[0], mm[1]), fmaxf(mm[2], mm[3]));
        float den = 0.f, w[4];
#pragma unroll
        for (int s = 0; s < 4; s++) { w[s] = exp2f(mm[s] - M); den += ll[s] * w[s]; }
        float accv[8];
#pragma unroll
        for (int e = 0; e < 8; e++) accv[e] = 0.f;
#pragma unroll
        for (int s = 0; s < 4; s++) {
            bf16x8 pv = *(const bf16x8*)(po + ((size_t)s * 16384 + m) * 256 + col8 * 8);
#pragma unroll
            for (int e = 0; e < 8; e++) accv[e] += w[s] * (float)pv[e];
        }
        float rinv = 1.f / den;
        bf16x8 o;
#pragma unroll
        for (int e = 0; e < 8; e++) o[e] = (__bf16)(accv[e] * rinv);
        *(bf16x8*)&atile[row][col8 * 8] = o;
    }
    bf16x8 bfr[4][8];
#pragma unroll
    for (int ct = 0; ct < 4; ct++)
#pragma unroll
        for (int kf = 0; kf < 8; kf++)
            bfr[ct][kf] = *(const bf16x8*)(wpl + ((((size_t)(ntbase + ct) * 8 + kf) * 4 + quad) * 16 + l16) * 8);
    __syncthreads();

    f32x4 acc[4][4];
#pragma unroll
    for (int mt = 0; mt < 4; mt++)
#pragma unroll
        for (int ct = 0; ct < 4; ct++)
#pragma unroll
            for (int r = 0; r < 4; r++) acc[mt][ct][r] = 0.f;
#pragma unroll
    for (int kf = 0; kf < 8; kf++) {
        bf16x8 af[4];
#pragma unroll
        for (int mt = 0; mt < 4; mt++)
            af[mt] = *(const bf16x8*)&atile[mt * 16 + l16][kf * 32 + quad * 8];
#pragma unroll
        for (int mt = 0; mt < 4; mt++)
#pragma unroll
            for (int ct = 0; ct < 4; ct++)
                acc[mt][ct] = MFMA16(af[mt], bfr[ct][kf], acc[mt][ct]);
    }
#pragma unroll
    for (int mt = 0; mt < 4; mt++) {
#pragma unroll
        for (int ct = 0; ct < 4; ct++) {
            int c = (ntbase + ct) * 16 + l16;
            float bias_v = bp[c];
#pragma unroll
            for (int r = 0; r < 4; r++) {
                int m = m0 + mt * 16 + quad * 4 + r;
                size_t idx = (size_t)m * 256 + c;
                out[idx] = out[idx] + acc[mt][ct][r] + bias_v;
            }
        }
    }
}

extern "C" void kernel_launch(void* const* d_in, const int* in_sizes, int n_in,
                              void* d_out, int out_size, void* d_ws, size_t ws_size,
                              hipStream_t stream) {
    const float* x     = (const float*)d_in[0];
    const float* gamma = (const float*)d_in[1];
    const float* beta  = (const float*)d_in[2];
    const float* Wq    = (const float*)d_in[3];
    const float* bq    = (const float*)d_in[4];
    const float* Wk    = (const float*)d_in[5];
    const float* bk    = (const float*)d_in[6];
    const float* Wv    = (const float*)d_in[7];
    const float* bv    = (const float*)d_in[8];
    const float* Wp    = (const float*)d_in[9];
    const float* bp    = (const float*)d_in[10];
    float* out = (float*)d_out;

    char* ws = (char*)d_ws;
    __bf16* xn_bf   = (__bf16*)(ws);                    //  8,388,608 B
    __bf16* wt      = (__bf16*)(ws + 8388608);          //    524,288 B (fragment-linear)
    __bf16* qbuf    = (__bf16*)(ws + 8912896);          //  8,388,608 B
    __bf16* kbuf    = (__bf16*)(ws + 17301504);         //  8,388,608 B
    __bf16* vtbuf   = (__bf16*)(ws + 25690112);         //  8,388,608 B
    __bf16* po      = (__bf16*)(ws + 34078720);         // 33,554,432 B
    float*  ml      = (float*)(ws + 67633152);          //    524,288 B
    float*  pstats  = (float*)(ws + 68157440);          //      4,096 B
    float*  gstats  = (float*)(ws + 68161536);          //        256 B

    gn_stats1<<<512, 256, 0, stream>>>(x, pstats);
    gn_stats2<<<1, 64, 0, stream>>>(pstats, gstats);
    gn_norm<<<4096, 256, 0, stream>>>(x, gamma, beta, gstats, out, xn_bf);
    prep_w<<<1024, 256, 0, stream>>>(Wq, Wk, Wv, Wp, wt);
    qkv_gemm<<<dim3(256, 2, 3), 128, 0, stream>>>(xn_bf, wt, bq, bk, bv, qbuf, kbuf, vtbuf);
    flash_attn<<<512, 256, 0, stream>>>(qbuf, kbuf, vtbuf, po, ml);
    proj_gemm<<<dim3(256, 2), 128, 0, stream>>>(po, ml, wt + 3 * 65536, bp, out);
}

// Round 4
// 255.918 us; speedup vs baseline: 1.5613x; 1.0666x over previous
//
#include <hip/hip_runtime.h>
#include <hip/hip_bf16.h>

typedef __bf16 bf16x8 __attribute__((ext_vector_type(8)));
typedef __bf16 bf16x4 __attribute__((ext_vector_type(4)));
typedef float f32x4 __attribute__((ext_vector_type(4)));
typedef float f32x16 __attribute__((ext_vector_type(16)));

#define MFMA16(a,b,c) __builtin_amdgcn_mfma_f32_16x16x32_bf16((a),(b),(c),0,0,0)
#define MFMA32(a,b,c) __builtin_amdgcn_mfma_f32_32x32x16_bf16((a),(b),(c),0,0,0)

// async global->LDS, 16B per lane; lds dst = wave-uniform base + lane*16
__device__ __forceinline__ void gload_lds16(const void* g, void* l) {
    __builtin_amdgcn_global_load_lds((const __attribute__((address_space(1))) unsigned int*)g,
                                     (__attribute__((address_space(3))) unsigned int*)l, 16, 0, 0);
}

// ---------------- GroupNorm stats, stage 1 ----------------
__global__ __launch_bounds__(256) void gn_stats1(const float* __restrict__ x,
                                                 float* __restrict__ pstats) {
    int blk = blockIdx.x;            // 0..511
    int bg = blk >> 4, sl = blk & 15;
    int b = bg >> 3, g = bg & 7;
    const float* base = x + ((size_t)b * 4096 + sl * 256) * 256 + g * 32;
    float s = 0.f, s2 = 0.f;
    for (int i = threadIdx.x; i < 2048; i += 256) {
        int pos = i >> 3, f4 = i & 7;
        float4 v = *(const float4*)(base + (size_t)pos * 256 + f4 * 4);
        s  += v.x + v.y + v.z + v.w;
        s2 += v.x * v.x + v.y * v.y + v.z * v.z + v.w * v.w;
    }
    for (int off = 32; off; off >>= 1) {
        s  += __shfl_down(s, off);
        s2 += __shfl_down(s2, off);
    }
    __shared__ float red[8];
    int wave = threadIdx.x >> 6, lane = threadIdx.x & 63;
    if (lane == 0) { red[wave] = s; red[4 + wave] = s2; }
    __syncthreads();
    if (threadIdx.x == 0) {
        pstats[blk * 2]     = red[0] + red[1] + red[2] + red[3];
        pstats[blk * 2 + 1] = red[4] + red[5] + red[6] + red[7];
    }
}

// ---------------- GroupNorm stats, stage 2 ----------------
__global__ void gn_stats2(const float* __restrict__ pstats, float* __restrict__ stats) {
    int bg = threadIdx.x;
    if (bg < 32) {
        float S = 0.f, S2 = 0.f;
        for (int sl = 0; sl < 16; sl++) {
            S  += pstats[(bg * 16 + sl) * 2];
            S2 += pstats[(bg * 16 + sl) * 2 + 1];
        }
        const float invN = 1.f / 131072.f;
        float mean = S * invN;
        float var = S2 * invN - mean * mean;
        stats[bg * 2] = mean;
        stats[bg * 2 + 1] = rsqrtf(var + 1e-3f);
    }
}

// ---------------- GroupNorm normalize ----------------
__global__ __launch_bounds__(256) void gn_norm(const float* __restrict__ x,
                                               const float* __restrict__ gamma,
                                               const float* __restrict__ beta,
                                               const float* __restrict__ stats,
                                               float* __restrict__ xn_f32,
                                               __bf16* __restrict__ xn_bf) {
    size_t idx = (size_t)blockIdx.x * 256 + threadIdx.x;
    int c4 = (int)(idx & 63);
    int row = (int)(idx >> 6);
    int b = row >> 12;
    int g = c4 >> 3;
    float mean = stats[(b * 8 + g) * 2];
    float rstd = stats[(b * 8 + g) * 2 + 1];
    float4 xv = ((const float4*)x)[idx];
    float4 ga = ((const float4*)gamma)[c4];
    float4 be = ((const float4*)beta)[c4];
    float4 r;
    r.x = (xv.x - mean) * rstd * ga.x + be.x;
    r.y = (xv.y - mean) * rstd * ga.y + be.y;
    r.z = (xv.z - mean) * rstd * ga.z + be.z;
    r.w = (xv.w - mean) * rstd * ga.w + be.w;
    ((float4*)xn_f32)[idx] = r;
    bf16x4 o;
    o[0] = (__bf16)r.x; o[1] = (__bf16)r.y; o[2] = (__bf16)r.z; o[3] = (__bf16)r.w;
    *(bf16x4*)(xn_bf + idx * 4) = o;
}

// ---------------- Weight prep: fp32 [k][n] -> bf16 fragment-linear ----------------
__global__ __launch_bounds__(256) void prep_w(const float* __restrict__ Wq,
                                              const float* __restrict__ Wk,
                                              const float* __restrict__ Wv,
                                              const float* __restrict__ Wp,
                                              __bf16* __restrict__ wt) {
    int o = blockIdx.x * 256 + threadIdx.x;  // 0..262143
    int w = o >> 16;
    int rem = o & 65535;
    int nt   = rem >> 12;
    int kf   = (rem >> 9) & 7;
    int quad = (rem >> 7) & 3;
    int l16  = (rem >> 3) & 15;
    int j    = rem & 7;
    int n = nt * 16 + l16;
    int k = kf * 32 + quad * 8 + j;
    const float* W = (w == 0) ? Wq : (w == 1) ? Wk : (w == 2) ? Wv : Wp;
    wt[o] = (__bf16)W[k * 256 + n];
}

// ---------------- QKV GEMM: LDS A-tile; v stored transposed via LDS bounce ----------------
__global__ __launch_bounds__(128, 2) void qkv_gemm(const __bf16* __restrict__ xn,
                                                   const __bf16* __restrict__ wt,
                                                   const float* __restrict__ bq,
                                                   const float* __restrict__ bk,
                                                   const float* __restrict__ bv,
                                                   __bf16* __restrict__ qout,
                                                   __bf16* __restrict__ kout,
                                                   __bf16* __restrict__ vtout) {
    __shared__ __bf16 atile[64][264];
    int w = blockIdx.z;
    const __bf16* Wl = wt + (size_t)w * 65536;
    int tid = threadIdx.x;
    int wave = tid >> 6, lane = tid & 63;
    int quad = lane >> 4, l16 = lane & 15;
    int m0 = blockIdx.x * 64;
    int ntbase = blockIdx.y * 8 + wave * 4;

#pragma unroll
    for (int i = 0; i < 16; i++) {
        int c = tid + 128 * i;
        int row = c >> 5, col = (c & 31) * 8;
        *(bf16x8*)&atile[row][col] = *(const bf16x8*)(xn + (size_t)(m0 + row) * 256 + col);
    }
    bf16x8 bfr[4][8];
#pragma unroll
    for (int ct = 0; ct < 4; ct++)
#pragma unroll
        for (int kf = 0; kf < 8; kf++)
            bfr[ct][kf] = *(const bf16x8*)(Wl + ((((size_t)(ntbase + ct) * 8 + kf) * 4 + quad) * 16 + l16) * 8);
    __syncthreads();

    f32x4 acc[4][4];
#pragma unroll
    for (int mt = 0; mt < 4; mt++)
#pragma unroll
        for (int ct = 0; ct < 4; ct++)
#pragma unroll
            for (int r = 0; r < 4; r++) acc[mt][ct][r] = 0.f;
#pragma unroll
    for (int kf = 0; kf < 8; kf++) {
        bf16x8 af[4];
#pragma unroll
        for (int mt = 0; mt < 4; mt++)
            af[mt] = *(const bf16x8*)&atile[mt * 16 + l16][kf * 32 + quad * 8];
#pragma unroll
        for (int mt = 0; mt < 4; mt++)
#pragma unroll
            for (int ct = 0; ct < 4; ct++)
                acc[mt][ct] = MFMA16(af[mt], bfr[ct][kf], acc[mt][ct]);
    }

    if (w == 2) {
        // transposed store via LDS bounce (coalesced 16B stores)
        __syncthreads();   // all waves done reading atile
        __bf16 (*vtl)[70] = (__bf16(*)[70])atile;    // 128 c x (64 n + pad)
#pragma unroll
        for (int mt = 0; mt < 4; mt++) {
#pragma unroll
            for (int ct = 0; ct < 4; ct++) {
                int cl = (wave * 4 + ct) * 16 + l16;   // 0..127 block-local channel
                float bias_v = bv[blockIdx.y * 128 + cl];
                bf16x4 pv;
#pragma unroll
                for (int r = 0; r < 4; r++) pv[r] = (__bf16)(acc[mt][ct][r] + bias_v);
                *(bf16x4*)&vtl[cl][mt * 16 + quad * 4] = pv;
            }
        }
        __syncthreads();
        int bb = m0 >> 12, n0g = m0 & 4095;
#pragma unroll
        for (int j = 0; j < 8; j++) {
            int chunk = tid + 128 * j;          // 0..1023
            int cl = chunk >> 3, n8 = chunk & 7;
            *(bf16x8*)(vtout + ((size_t)(bb * 256 + blockIdx.y * 128 + cl)) * 4096 + n0g + n8 * 8)
                = *(const bf16x8*)&vtl[cl][n8 * 8];
        }
    } else {
        const float* bias = (w == 0) ? bq : bk;
        // q pre-scaled by (1/16)*log2(e) so flash softmax runs in exp2 domain
        const float qscale = 0.09016844f;
#pragma unroll
        for (int mt = 0; mt < 4; mt++) {
#pragma unroll
            for (int ct = 0; ct < 4; ct++) {
                int c = (ntbase + ct) * 16 + l16;
                float bias_v = bias[c];
#pragma unroll
                for (int r = 0; r < 4; r++) {
                    int m = m0 + mt * 16 + quad * 4 + r;
                    float val = acc[mt][ct][r] + bias_v;
                    if (w == 0) qout[(size_t)m * 256 + c] = (__bf16)(val * qscale);
                    else        kout[(size_t)m * 256 + c] = (__bf16)val;
                }
            }
        }
    }
}

// ---------------- Flash attention v12: v9 skeleton, V via source-swizzled gload_lds,
// QK^T as two independent 8-MFMA chains.  Loop has zero ds_writes and a single
// pre-barrier vmcnt(0)+lgkmcnt(0); staging (8 gload_lds, K then V) issues at body
// start and is covered by the QK/softmax/PV body.
// V LDS layout: linear [256 ch][4 chunks of 16B] per tile; physical chunk p of
// channel ch holds logical key-chunk p ^ sw(ch), sw(ch) = (ch ^ (ch>>2)) & 3.
// PV reads logical chunk c at physical c ^ sw -> 4-way bank conflict (accepted).
__global__ __launch_bounds__(256, 2) void flash_attn(const __bf16* __restrict__ q,
                                                     const __bf16* __restrict__ k,
                                                     const __bf16* __restrict__ vt,
                                                     __bf16* __restrict__ po,
                                                     float* __restrict__ ml) {
    __shared__ __align__(16) char smem[69632];
    // K dbuf at smem+0 / +16384 (XOR-swizzled 16B chunks, cp holds cl = cp ^ row)
    // V dbuf at smem+32768 / +49152, 16384 B each, layout above
    __bf16 (*otr)[32][264] = (__bf16(*)[32][264])smem;      // epilogue overlay

    const int tid = threadIdx.x;
    const int wave = tid >> 6, lane = tid & 63;
    const int l32 = lane & 31, h = lane >> 5;
    // XCD-aware swizzle (T1): chunked remap, nwg=512 divisible by 8 -> bijective
    const int fid = blockIdx.x;
    const int cid = ((fid & 7) << 6) | (fid >> 3);
    const int qt  = cid & 31;
    const int ksb = cid >> 5;        // 0..15
    const int ks  = ksb & 3, b = ksb >> 2;
    const int row0 = qt * 128 + wave * 32;
    const size_t rowg0 = (size_t)b * 4096 + row0;

    const char*   kb = (const char*)(k + ((size_t)b * 4096 + ks * 1024) * 256);
    const __bf16* vb = vt + (size_t)b * 256 * 4096 + ks * 1024;

    int koff[4];
#pragma unroll
    for (int i = 0; i < 4; i++) {
        int P = wave * 256 + i * 64 + lane;
        int r = P >> 5, cp = P & 31;
        koff[i] = r * 512 + (cp ^ r) * 16;
    }
    const int kldsoff = wave * 4096;

    // V staging: wave w covers channels [w*64, w*64+64); instr i covers 16 channels.
    // lane = r4*4 + c4; fetches logical chunk c4 ^ sw(r4) so LDS physical chunk c4
    // holds logical c4 ^ sw.
    const int r4 = (lane >> 2) & 15, c4v = lane & 3;
    const int swl = (r4 ^ (r4 >> 2)) & 3;
    int voff[4];
#pragma unroll
    for (int i = 0; i < 4; i++) {
        int ch = wave * 64 + i * 16 + r4;
        voff[i] = ch * 4096 + (c4v ^ swl) * 8;
    }
    const int vldsoff = wave * 4096;

    bf16x8 qf[16];
    const __bf16* qbase = q + (rowg0 + l32) * 256 + h * 8;
#pragma unroll
    for (int s = 0; s < 16; s++) qf[s] = *(const bf16x8*)(qbase + s * 16);

    f32x16 acc[8];
#pragma unroll
    for (int ct = 0; ct < 8; ct++)
#pragma unroll
        for (int r = 0; r < 16; r++) acc[ct][r] = 0.f;
    float mi = -1e30f, li = 0.f;

    // ---- prologue: stage tile 0 (K then V, all async) ----
#pragma unroll
    for (int i = 0; i < 4; i++)
        gload_lds16(kb + koff[i], smem + kldsoff + i * 1024);
#pragma unroll
    for (int i = 0; i < 4; i++)
        gload_lds16(vb + voff[i], smem + 32768 + vldsoff + i * 1024);
    asm volatile("s_waitcnt vmcnt(0)" ::: "memory");
    __builtin_amdgcn_sched_barrier(0);
    __builtin_amdgcn_s_barrier();

    for (int it = 0; it < 32; ++it) {
        const int cur = it & 1;
        const char* kcur = smem + (cur ? 16384 : 0);
        const char* vcur = smem + 32768 + (cur ? 16384 : 0);

        // ---- stage tile it+1 (async; buffers freed by last barrier) ----
        if (it + 1 < 32) {
            const char* kg = kb + (size_t)(it + 1) * 16384;
            char* kw = smem + (cur ? 0 : 16384);
#pragma unroll
            for (int i = 0; i < 4; i++)
                gload_lds16(kg + koff[i], kw + kldsoff + i * 1024);
            const int kn = (it + 1) * 32;
            char* vw = smem + 32768 + (cur ? 0 : 16384);
#pragma unroll
            for (int i = 0; i < 4; i++)
                gload_lds16(vb + voff[i] + kn, vw + vldsoff + i * 1024);
        }

        // ---- S^T = K . Q^T: two independent 8-MFMA chains ----
        f32x16 s0_, s1_;
#pragma unroll
        for (int r = 0; r < 16; r++) { s0_[r] = 0.f; s1_[r] = 0.f; }
#pragma unroll
        for (int u = 0; u < 8; u++) {
            {
                int cl = 2 * u + h;
                bf16x8 ka = *(const bf16x8*)(kcur + l32 * 512 + ((cl ^ l32) << 4));
                s0_ = MFMA32(ka, qf[u], s0_);
            }
            {
                int cl = 2 * (u + 8) + h;
                bf16x8 ka = *(const bf16x8*)(kcur + l32 * 512 + ((cl ^ l32) << 4));
                s1_ = MFMA32(ka, qf[u + 8], s1_);
            }
        }
        // ---- merge chains + online softmax (exp2 domain; defer-max T13) ----
#pragma unroll
        for (int r = 0; r < 16; r++) s0_[r] += s1_[r];
        float mx = s0_[0];
#pragma unroll
        for (int r = 1; r < 16; r++) mx = fmaxf(mx, s0_[r]);
        mx = fmaxf(mx, __shfl_xor(mx, 32));
        if (__ballot(mx > mi + 8.0f)) {
            float mnew = fmaxf(mi, mx);
            float alpha = exp2f(mi - mnew);
#pragma unroll
            for (int ct = 0; ct < 8; ct++)
#pragma unroll
                for (int r = 0; r < 16; r++) acc[ct][r] *= alpha;
            li *= alpha;
            mi = mnew;
        }
        float rs = 0.f;
#pragma unroll
        for (int r = 0; r < 16; r++) { float p = exp2f(s0_[r] - mi); s0_[r] = p; rs += p; }
        rs += __shfl_xor(rs, 32);
        li += rs;
        bf16x8 pf0, pf1;
#pragma unroll
        for (int j = 0; j < 8; j++) { pf0[j] = (__bf16)s0_[j]; pf1[j] = (__bf16)s0_[8 + j]; }

        // ---- O^T += V^T . P (sigma-permuted V A-frags; source-swizzled chunks) ----
        {
            const int sb = ((l32 ^ (l32 >> 2)) & 3) << 4;   // swr*16
            const char* vrow = vcur + l32 * 64 + h * 8;
            __builtin_amdgcn_s_setprio(1);
#pragma unroll
            for (int ct = 0; ct < 8; ct++) {
                const char* vr2 = vrow + ct * 2048;
                bf16x4 a00 = *(const bf16x4*)(vr2 + sb);
                bf16x4 a01 = *(const bf16x4*)(vr2 + (sb ^ 16));
                bf16x8 va0 = __builtin_shufflevector(a00, a01, 0, 1, 2, 3, 4, 5, 6, 7);
                acc[ct] = MFMA32(va0, pf0, acc[ct]);
                bf16x4 a10 = *(const bf16x4*)(vr2 + (sb ^ 32));
                bf16x4 a11 = *(const bf16x4*)(vr2 + (sb ^ 48));
                bf16x8 va1 = __builtin_shufflevector(a10, a11, 0, 1, 2, 3, 4, 5, 6, 7);
                acc[ct] = MFMA32(va1, pf1, acc[ct]);
            }
            __builtin_amdgcn_s_setprio(0);
        }

        // ---- all staging for it+1 must land; own ds reads drained ----
        asm volatile("s_waitcnt vmcnt(0) lgkmcnt(0)" ::: "memory");
        __builtin_amdgcn_sched_barrier(0);
        __builtin_amdgcn_s_barrier();
    }

    // epilogue: transpose O^T -> row-major via wave-private LDS region
#pragma unroll
    for (int ct = 0; ct < 8; ct++) {
#pragma unroll
        for (int pk = 0; pk < 4; pk++) {
            bf16x4 op;
            op[0] = (__bf16)acc[ct][pk * 4];     op[1] = (__bf16)acc[ct][pk * 4 + 1];
            op[2] = (__bf16)acc[ct][pk * 4 + 2]; op[3] = (__bf16)acc[ct][pk * 4 + 3];
            *(bf16x4*)&otr[wave][l32][ct * 32 + pk * 8 + h * 4] = op;
        }
    }
    if (lane < 32) {
        float2 v; v.x = mi; v.y = li;    // mi in log2 domain
        *(float2*)&ml[((size_t)ks * 16384 + rowg0 + l32) * 2] = v;
    }
    __syncthreads();
    __bf16* pobase = po + ((size_t)ks * 16384 + rowg0) * 256;
    const int rr = lane >> 1, half = lane & 1;
#pragma unroll
    for (int j = 0; j < 16; j++) {
        bf16x8 val = *(const bf16x8*)&otr[wave][rr][half * 128 + j * 8];
        *(bf16x8*)(pobase + (size_t)rr * 256 + half * 128 + j * 8) = val;
    }
}

// ---------------- Projection GEMM + fused 4-way merge + bias + residual ----------------
__global__ __launch_bounds__(128, 2) void proj_gemm(const __bf16* __restrict__ po,
                                                    const float* __restrict__ ml,
                                                    const __bf16* __restrict__ wpl,
                                                    const float* __restrict__ bp,
                                                    float* __restrict__ out) {
    __shared__ __bf16 atile[64][264];
    int tid = threadIdx.x;
    int wave = tid >> 6, lane = tid & 63;
    int quad = lane >> 4, l16 = lane & 15;
    int m0 = blockIdx.x * 64;
    int ntbase = blockIdx.y * 8 + wave * 4;

    // stage A-tile = merged attention output (4 key-split partials, exp2 domain)
#pragma unroll
    for (int i = 0; i < 16; i++) {
        int c = tid + 128 * i;
        int row = c >> 5, col8 = c & 31;
        int m = m0 + row;
        float mm[4], ll[4];
#pragma unroll
        for (int s = 0; s < 4; s++) {
            float2 v = *(const float2*)&ml[((size_t)s * 16384 + m) * 2];
            mm[s] = v.x; ll[s] = v.y;
        }
        float M = fmaxf(fmaxf(mm[0], mm[1]), fmaxf(mm[2], mm[3]));
        float den = 0.f, w[4];
#pragma unroll
        for (int s = 0; s < 4; s++) { w[s] = exp2f(mm[s] - M); den += ll[s] * w[s]; }
        float accv[8];
#pragma unroll
        for (int e = 0; e < 8; e++) accv[e] = 0.f;
#pragma unroll
        for (int s = 0; s < 4; s++) {
            bf16x8 pv = *(const bf16x8*)(po + ((size_t)s * 16384 + m) * 256 + col8 * 8);
#pragma unroll
            for (int e = 0; e < 8; e++) accv[e] += w[s] * (float)pv[e];
        }
        float rinv = 1.f / den;
        bf16x8 o;
#pragma unroll
        for (int e = 0; e < 8; e++) o[e] = (__bf16)(accv[e] * rinv);
        *(bf16x8*)&atile[row][col8 * 8] = o;
    }
    bf16x8 bfr[4][8];
#pragma unroll
    for (int ct = 0; ct < 4; ct++)
#pragma unroll
        for (int kf = 0; kf < 8; kf++)
            bfr[ct][kf] = *(const bf16x8*)(wpl + ((((size_t)(ntbase + ct) * 8 + kf) * 4 + quad) * 16 + l16) * 8);
    __syncthreads();

    f32x4 acc[4][4];
#pragma unroll
    for (int mt = 0; mt < 4; mt++)
#pragma unroll
        for (int ct = 0; ct < 4; ct++)
#pragma unroll
            for (int r = 0; r < 4; r++) acc[mt][ct][r] = 0.f;
#pragma unroll
    for (int kf = 0; kf < 8; kf++) {
        bf16x8 af[4];
#pragma unroll
        for (int mt = 0; mt < 4; mt++)
            af[mt] = *(const bf16x8*)&atile[mt * 16 + l16][kf * 32 + quad * 8];
#pragma unroll
        for (int mt = 0; mt < 4; mt++)
#pragma unroll
            for (int ct = 0; ct < 4; ct++)
                acc[mt][ct] = MFMA16(af[mt], bfr[ct][kf], acc[mt][ct]);
    }
#pragma unroll
    for (int mt = 0; mt < 4; mt++) {
#pragma unroll
        for (int ct = 0; ct < 4; ct++) {
            int c = (ntbase + ct) * 16 + l16;
            float bias_v = bp[c];
#pragma unroll
            for (int r = 0; r < 4; r++) {
                int m = m0 + mt * 16 + quad * 4 + r;
                size_t idx = (size_t)m * 256 + c;
                out[idx] = out[idx] + acc[mt][ct][r] + bias_v;
            }
        }
    }
}

extern "C" void kernel_launch(void* const* d_in, const int* in_sizes, int n_in,
                              void* d_out, int out_size, void* d_ws, size_t ws_size,
                              hipStream_t stream) {
    const float* x     = (const float*)d_in[0];
    const float* gamma = (const float*)d_in[1];
    const float* beta  = (const float*)d_in[2];
    const float* Wq    = (const float*)d_in[3];
    const float* bq    = (const float*)d_in[4];
    const float* Wk    = (const float*)d_in[5];
    const float* bk    = (const float*)d_in[6];
    const float* Wv    = (const float*)d_in[7];
    const float* bv    = (const float*)d_in[8];
    const float* Wp    = (const float*)d_in[9];
    const float* bp    = (const float*)d_in[10];
    float* out = (float*)d_out;

    char* ws = (char*)d_ws;
    __bf16* xn_bf   = (__bf16*)(ws);                    //  8,388,608 B
    __bf16* wt      = (__bf16*)(ws + 8388608);          //    524,288 B (fragment-linear)
    __bf16* qbuf    = (__bf16*)(ws + 8912896);          //  8,388,608 B
    __bf16* kbuf    = (__bf16*)(ws + 17301504);         //  8,388,608 B
    __bf16* vtbuf   = (__bf16*)(ws + 25690112);         //  8,388,608 B
    __bf16* po      = (__bf16*)(ws + 34078720);         // 33,554,432 B
    float*  ml      = (float*)(ws + 67633152);          //    524,288 B
    float*  pstats  = (float*)(ws + 68157440);          //      4,096 B
    float*  gstats  = (float*)(ws + 68161536);          //        256 B

    gn_stats1<<<512, 256, 0, stream>>>(x, pstats);
    gn_stats2<<<1, 64, 0, stream>>>(pstats, gstats);
    gn_norm<<<4096, 256, 0, stream>>>(x, gamma, beta, gstats, out, xn_bf);
    prep_w<<<1024, 256, 0, stream>>>(Wq, Wk, Wv, Wp, wt);
    qkv_gemm<<<dim3(256, 2, 3), 128, 0, stream>>>(xn_bf, wt, bq, bk, bv, qbuf, kbuf, vtbuf);
    flash_attn<<<512, 256, 0, stream>>>(qbuf, kbuf, vtbuf, po, ml);
    proj_gemm<<<dim3(256, 2), 128, 0, stream>>>(po, ml, wt + 3 * 65536, bp, out);
}